// Round 1
// baseline (1837.046 us; speedup 1.0000x reference)
//
#include <hip/hip_runtime.h>
#include <math.h>

#define GN 400
#define NPER 50
#define NN 20000
#define EE 240000
#define LL 4

__device__ __forceinline__ float silu_f(float x) {
  return x / (1.0f + __expf(-x));
}

// ---------------------------------------------------------------------------
// Time embedding MLP + per-layer per-graph t-projections (tiny: 400 graphs)
// tE[l][g] = temb[g] @ eW1[l][257:385] + eb1[l]   (bias folded in)
// tN[l][g] = temb[g] @ nW1[l][256:384] + nb1[l]
// ---------------------------------------------------------------------------
__global__ __launch_bounds__(128) void time_kernel(
    const float* __restrict__ t,
    const float* __restrict__ tm_W1, const float* __restrict__ tm_b1,
    const float* __restrict__ tm_W2, const float* __restrict__ tm_b2,
    const float* __restrict__ eW1, const float* __restrict__ eb1,
    const float* __restrict__ nW1, const float* __restrict__ nb1,
    float* __restrict__ temb, float* __restrict__ tE, float* __restrict__ tN)
{
  int g = blockIdx.x;
  int j = threadIdx.x;
  __shared__ float x[128];
  __shared__ float hid[256];
  __shared__ float te[128];
  float tv = t[g];
  if (j < 64) {
    // freqs = exp(j * (-ln(10000)/63))
    float f = __expf((float)j * (-9.210340371976184f / 63.0f));
    float a = tv * f;
    x[j] = sinf(a);
    x[j + 64] = cosf(a);
  }
  __syncthreads();
  for (int o = j; o < 256; o += 128) {
    float acc = tm_b1[o];
    for (int k = 0; k < 128; ++k) acc = fmaf(x[k], tm_W1[k * 256 + o], acc);
    hid[o] = silu_f(acc);
  }
  __syncthreads();
  {
    float acc = tm_b2[j];
    for (int k = 0; k < 256; ++k) acc = fmaf(hid[k], tm_W2[k * 128 + j], acc);
    te[j] = acc;
    temb[g * 128 + j] = acc;
  }
  __syncthreads();
  for (int l = 0; l < LL; ++l) {
    const float* W = eW1 + (l * 385 + 257) * 128;  // t_edges rows of eW1
    float acc = eb1[l * 128 + j];
    for (int k = 0; k < 128; ++k) acc = fmaf(te[k], W[k * 128 + j], acc);
    tE[(l * GN + g) * 128 + j] = acc;
    const float* Wn = nW1 + (l * 384 + 256) * 128; // t_nodes rows of nW1
    float acc2 = nb1[l * 128 + j];
    for (int k = 0; k < 128; ++k) acc2 = fmaf(te[k], Wn[k * 128 + j], acc2);
    tN[(l * GN + g) * 128 + j] = acc2;
  }
}

// ---------------------------------------------------------------------------
// Generic node-level GEMM: out[n, 0:128] (op)= act( [A0|A1][n] @ W + bias + extra[g(n)] )
// A = concat of A0 (K0 cols) and A1 (K1 cols, optional row-gather via idx1).
// Tile: 32 rows x 128 cols per block, 256 threads, chunked K (multiples of 32).
// ---------------------------------------------------------------------------
__global__ __launch_bounds__(256) void gemm_node(
    const float* __restrict__ A0, int K0,
    const float* __restrict__ A1, int K1, const int* __restrict__ idx1, int a1rows,
    const float* __restrict__ W, const float* __restrict__ bias,
    const float* __restrict__ extra,
    float* __restrict__ out, int ldout, int act, int addto)
{
  __shared__ float Ast[32 * 36];     // transposed A chunk: [k][row], row-stride 36
  __shared__ float Wsf[32 * 128];    // W chunk: [k][col]
  int t = threadIdx.x;
  int rowBase = blockIdx.x * 32;
  int tx = t & 31;        // col quad: cols tx*4..+3
  int ty = t >> 5;        // row quad: rows ty*4..+3
  int Ktot = K0 + K1;
  float acc[4][4] = {{0.f, 0.f, 0.f, 0.f}, {0.f, 0.f, 0.f, 0.f},
                     {0.f, 0.f, 0.f, 0.f}, {0.f, 0.f, 0.f, 0.f}};
  int lr = t >> 3, lkq = t & 7;  // A-stage mapping: row lr, k-quad lkq

  for (int kk = 0; kk < Ktot; kk += 32) {
    __syncthreads();
    {
      int grow = rowBase + lr;
      int kcol = kk + lkq * 4;
      float4 v;
      if (kcol < K0) {
        v = *(const float4*)(A0 + grow * K0 + kcol);
      } else {
        int arow = grow;
        if (idx1) { arow = idx1[grow]; arow = min(max(arow, 0), a1rows - 1); }
        v = *(const float4*)(A1 + arow * K1 + (kcol - K0));
      }
      Ast[(lkq * 4 + 0) * 36 + lr] = v.x;
      Ast[(lkq * 4 + 1) * 36 + lr] = v.y;
      Ast[(lkq * 4 + 2) * 36 + lr] = v.z;
      Ast[(lkq * 4 + 3) * 36 + lr] = v.w;
    }
    for (int fi = t; fi < 1024; fi += 256)
      ((float4*)Wsf)[fi] = ((const float4*)W)[kk * 32 + fi];
    __syncthreads();
#pragma unroll
    for (int k = 0; k < 32; ++k) {
      float4 a = *(const float4*)&Ast[k * 36 + ty * 4];
      float4 w = *(const float4*)&Wsf[k * 128 + tx * 4];
      float av[4] = {a.x, a.y, a.z, a.w};
      float wv[4] = {w.x, w.y, w.z, w.w};
#pragma unroll
      for (int i = 0; i < 4; ++i)
#pragma unroll
        for (int q = 0; q < 4; ++q)
          acc[i][q] = fmaf(av[i], wv[q], acc[i][q]);
    }
  }
#pragma unroll
  for (int i = 0; i < 4; ++i) {
    int grow = rowBase + ty * 4 + i;
#pragma unroll
    for (int q = 0; q < 4; ++q) {
      int col = tx * 4 + q;
      float v = acc[i][q];
      if (bias) v += bias[col];
      if (extra) v += extra[(grow / NPER) * 128 + col];
      if (act) v = silu_f(v);
      float* p = out + grow * ldout + col;
      if (addto) *p += v; else *p = v;
    }
  }
}

// ---------------------------------------------------------------------------
// LDS-resident [48,128]@[128,128] + bias + silu (edge message GEMM phase)
// m_in/m_out rows padded to 132 floats. Wsf is a 32x128 staging buffer.
// ---------------------------------------------------------------------------
__device__ __forceinline__ void lds_gemm_48(
    const float* __restrict__ Wg, const float* __restrict__ bias_g,
    const float* m_in, float* m_out, float* Wsf, int t)
{
  int tx = t & 31;   // cols tx*4..+3
  int ty = t >> 5;   // rows ty*6..+5
  float acc[6][4] = {{0.f,0.f,0.f,0.f},{0.f,0.f,0.f,0.f},{0.f,0.f,0.f,0.f},
                     {0.f,0.f,0.f,0.f},{0.f,0.f,0.f,0.f},{0.f,0.f,0.f,0.f}};
  for (int kk = 0; kk < 128; kk += 32) {
    __syncthreads();
    for (int fi = t; fi < 1024; fi += 256)
      ((float4*)Wsf)[fi] = ((const float4*)Wg)[kk * 32 + fi];
    __syncthreads();
#pragma unroll
    for (int k = 0; k < 32; ++k) {
      float4 w = *(const float4*)&Wsf[k * 128 + tx * 4];
#pragma unroll
      for (int r = 0; r < 6; ++r) {
        float a = m_in[(ty * 6 + r) * 132 + kk + k];
        acc[r][0] = fmaf(a, w.x, acc[r][0]);
        acc[r][1] = fmaf(a, w.y, acc[r][1]);
        acc[r][2] = fmaf(a, w.z, acc[r][2]);
        acc[r][3] = fmaf(a, w.w, acc[r][3]);
      }
    }
  }
  __syncthreads();
#pragma unroll
  for (int r = 0; r < 6; ++r) {
    int e = ty * 6 + r;
#pragma unroll
    for (int q = 0; q < 4; ++q) {
      int j = tx * 4 + q;
      m_out[e * 132 + j] = silu_f(acc[r][q] + bias_g[j]);
    }
  }
}

// ---------------------------------------------------------------------------
// Edge pipeline for one layer. Block = 4 nodes = 48 edges (edges of node n are
// exactly [12n, 12n+12) by construction; src/dst in same graph).
// m1 = silu(hA[src] + hB[dst] + dist_sq*w_d + tE[g])   (eb1 folded into tE)
// m2 = silu(m1 @ eW2 + eb2);  g_in = silu(m2 @ cW1 + cb1); gate = g_in . cW2
// m_i[n] = sum_e m2;  shift[n] (+)= sum_e diff/dist * gate
// ---------------------------------------------------------------------------
__global__ __launch_bounds__(256) void edge_kernel(
    const float* __restrict__ hAB, const float* __restrict__ coords,
    const int* __restrict__ edge_src,
    const float* __restrict__ eW1, const float* __restrict__ eW2,
    const float* __restrict__ eb2, const float* __restrict__ cW1,
    const float* __restrict__ cb1, const float* __restrict__ cW2,
    const float* __restrict__ tE,
    float* __restrict__ m_i, float* __restrict__ shift_out,
    int l, int addflag)
{
  __shared__ float m1[48 * 132];
  __shared__ float m2[48 * 132];
  __shared__ float Wsf[32 * 128];
  __shared__ float sdx[48], sdy[48], sdz[48], sds[48], sinv[48], sgate[48];
  __shared__ int ssrc[48];
  __shared__ float part[48][4];

  int t = threadIdx.x;
  int nbase = blockIdx.x * 4;
  int ebase = nbase * 12;
  const float* eW1_l = eW1 + (l * 385) * 128;
  const float* eW2_l = eW2 + l * 128 * 128;
  const float* cW1_l = cW1 + l * 128 * 128;
  const float* cW2_l = cW2 + l * 128;
  const float* eb2_l = eb2 + l * 128;
  const float* cb1_l = cb1 + l * 128;
  const float* tE_l  = tE  + l * GN * 128;

  if (t < 48) {
    int e = ebase + t;
    int src = edge_src[e];
    src = min(max(src, 0), NN - 1);
    int dst = nbase + t / 12;
    float dx = coords[src * 3 + 0] - coords[dst * 3 + 0];
    float dy = coords[src * 3 + 1] - coords[dst * 3 + 1];
    float dz = coords[src * 3 + 2] - coords[dst * 3 + 2];
    float ds = dx * dx + dy * dy + dz * dz;
    ssrc[t] = src;
    sdx[t] = dx; sdy[t] = dy; sdz[t] = dz; sds[t] = ds;
    sinv[t] = 1.0f / sqrtf(ds + 1e-8f);
  }
  __syncthreads();

  // Phase A: m1
  {
    const float* wd = eW1_l + 256 * 128;  // dist_sq row
    for (int idx = t; idx < 48 * 128; idx += 256) {
      int e = idx >> 7, j = idx & 127;
      int src = ssrc[e];
      int dst = nbase + (e / 12);
      int g = dst / NPER;
      float v = hAB[src * 256 + j] + hAB[dst * 256 + 128 + j]
              + sds[e] * wd[j] + tE_l[g * 128 + j];
      m1[e * 132 + j] = silu_f(v);
    }
  }
  __syncthreads();

  // Phase B: m2 = silu(m1 @ eW2 + eb2)
  lds_gemm_48(eW2_l, eb2_l, m1, m2, Wsf, t);
  __syncthreads();

  // Phase C: g_in = silu(m2 @ cW1 + cb1) -> reuse m1 buffer
  lds_gemm_48(cW1_l, cb1_l, m2, m1, Wsf, t);
  __syncthreads();

  // Phase D: gate = g_in . cW2
  if (t < 192) {
    int e = t >> 2, q = t & 3;
    float s = 0.f;
    for (int j = q * 32; j < q * 32 + 32; ++j) s = fmaf(m1[e * 132 + j], cW2_l[j], s);
    part[e][q] = s;
  }
  __syncthreads();
  if (t < 48) sgate[t] = part[t][0] + part[t][1] + part[t][2] + part[t][3];
  __syncthreads();

  // m_i: sum of m2 over each node's 12 edges
  for (int idx = t; idx < 4 * 128; idx += 256) {
    int nl = idx >> 7, j = idx & 127;
    float s = 0.f;
#pragma unroll
    for (int r = 0; r < 12; ++r) s += m2[(nl * 12 + r) * 132 + j];
    m_i[(nbase + nl) * 128 + j] = s;
  }
  // shift accumulation
  if (t < 12) {
    int nl = t / 3, c = t % 3;
    float s = 0.f;
    for (int r = 0; r < 12; ++r) {
      int e = nl * 12 + r;
      float comp = (c == 0) ? sdx[e] : ((c == 1) ? sdy[e] : sdz[e]);
      s = fmaf(comp * sinv[e], sgate[e], s);
    }
    int n = nbase + nl;
    if (addflag) shift_out[n * 3 + c] += s;
    else         shift_out[n * 3 + c] = s;
  }
}

extern "C" void kernel_launch(void* const* d_in, const int* in_sizes, int n_in,
                              void* d_out, int out_size, void* d_ws, size_t ws_size,
                              hipStream_t stream)
{
  const float* z_nodes     = (const float*)d_in[0];
  const float* t           = (const float*)d_in[1];
  const float* coords      = (const float*)d_in[2];
  const int*   species     = (const int*)d_in[3];
  const int*   edge_src    = (const int*)d_in[5];
  const float* species_emb = (const float*)d_in[7];
  const float* tm_W1 = (const float*)d_in[8];
  const float* tm_b1 = (const float*)d_in[9];
  const float* tm_W2 = (const float*)d_in[10];
  const float* tm_b2 = (const float*)d_in[11];
  const float* ne_W  = (const float*)d_in[12];
  const float* ne_b  = (const float*)d_in[13];
  const float* eW1   = (const float*)d_in[14];
  const float* eb1   = (const float*)d_in[15];
  const float* eW2   = (const float*)d_in[16];
  const float* eb2   = (const float*)d_in[17];
  const float* cW1   = (const float*)d_in[18];
  const float* cb1   = (const float*)d_in[19];
  const float* cW2   = (const float*)d_in[20];
  const float* nW1   = (const float*)d_in[21];
  const float* nb1   = (const float*)d_in[22];
  const float* nW2   = (const float*)d_in[23];
  const float* nb2   = (const float*)d_in[24];

  float* ws   = (float*)d_ws;
  float* temb = ws;               // 400*128            = 51200
  float* tEb  = ws + 51200;       // 4*400*128          = 204800
  float* tNb  = ws + 256000;      // 4*400*128          = 204800
  float* hAB  = ws + 460800;      // 20000*256          = 5120000
  float* m_i  = ws + 5580800;     // 20000*128          = 2560000
  float* z1   = hAB;              // alias: hAB dead once z1 is produced
  // total ws use: 8,140,800 floats (~31 MiB)

  float* outp  = (float*)d_out;
  float* shift = outp;            // [20000,3]
  float* h     = outp + 60000;    // [20000,128] final h lives in d_out

  // time embedding + per-graph projections
  time_kernel<<<GN, 128, 0, stream>>>(t, tm_W1, tm_b1, tm_W2, tm_b2,
                                      eW1, eb1, nW1, nb1, temb, tEb, tNb);
  // node encoder: h = [z | sp(species)] @ ne_W + ne_b
  gemm_node<<<NN / 32, 256, 0, stream>>>(z_nodes, 128, species_emb, 32, species, 119,
                                         ne_W, ne_b, nullptr, h, 128, 0, 0);

  for (int l = 0; l < LL; ++l) {
    // hA = h @ eW1[0:128], hB = h @ eW1[128:256]  (into hAB, ld 256)
    gemm_node<<<NN / 32, 256, 0, stream>>>(h, 128, nullptr, 0, nullptr, 0,
                                           eW1 + (l * 385 + 0) * 128, nullptr, nullptr,
                                           hAB, 256, 0, 0);
    gemm_node<<<NN / 32, 256, 0, stream>>>(h, 128, nullptr, 0, nullptr, 0,
                                           eW1 + (l * 385 + 128) * 128, nullptr, nullptr,
                                           hAB + 128, 256, 0, 0);
    // edge pipeline: messages, gate, m_i, shift accumulation
    edge_kernel<<<NN / 4, 256, 0, stream>>>(hAB, coords, edge_src,
                                            eW1, eW2, eb2, cW1, cb1, cW2, tEb,
                                            m_i, shift, l, (l > 0) ? 1 : 0);
    // z1 = silu([h | m_i] @ nW1[0:256] + tN)   (nb1 folded into tN)
    gemm_node<<<NN / 32, 256, 0, stream>>>(h, 128, m_i, 128, nullptr, NN,
                                           nW1 + l * 384 * 128, nullptr, tNb + l * 51200,
                                           z1, 128, 1, 0);
    // h += z1 @ nW2 + nb2
    gemm_node<<<NN / 32, 256, 0, stream>>>(z1, 128, nullptr, 0, nullptr, 0,
                                           nW2 + l * 128 * 128, nb2 + l * 128, nullptr,
                                           h, 128, 0, 1);
  }
}

// Round 2
// 715.963 us; speedup vs baseline: 2.5658x; 2.5658x over previous
//
#include <hip/hip_runtime.h>
#include <math.h>

#define GN 400
#define NPER 50
#define NN 20000
#define EE 240000
#define LL 4

typedef __attribute__((ext_vector_type(8))) short short8;
typedef __attribute__((ext_vector_type(4))) float f32x4;

__device__ __forceinline__ float silu_f(float x) {
  return x / (1.0f + __expf(-x));
}
__device__ __forceinline__ unsigned short f2bu(float f) {
  unsigned int u = __float_as_uint(f);
  unsigned int r = (u + 0x7fffu + ((u >> 16) & 1u)) >> 16;
  return (unsigned short)r;
}
__device__ __forceinline__ float bs2f(unsigned short s) {
  return __uint_as_float(((unsigned int)s) << 16);
}

// ---------------------------------------------------------------------------
// Time embedding MLP + per-layer per-graph t-projections (tiny: 400 graphs)
// tE[l][g] = temb[g] @ eW1[l][257:385] + eb1[l]   (bias folded in)
// tN[l][g] = temb[g] @ nW1[l][256:384] + nb1[l]
// ---------------------------------------------------------------------------
__global__ __launch_bounds__(128) void time_kernel(
    const float* __restrict__ t,
    const float* __restrict__ tm_W1, const float* __restrict__ tm_b1,
    const float* __restrict__ tm_W2, const float* __restrict__ tm_b2,
    const float* __restrict__ eW1, const float* __restrict__ eb1,
    const float* __restrict__ nW1, const float* __restrict__ nb1,
    float* __restrict__ temb, float* __restrict__ tE, float* __restrict__ tN)
{
  int g = blockIdx.x;
  int j = threadIdx.x;
  __shared__ float x[128];
  __shared__ float hid[256];
  __shared__ float te[128];
  float tv = t[g];
  if (j < 64) {
    float f = __expf((float)j * (-9.210340371976184f / 63.0f));
    float a = tv * f;
    x[j] = sinf(a);
    x[j + 64] = cosf(a);
  }
  __syncthreads();
  for (int o = j; o < 256; o += 128) {
    float acc = tm_b1[o];
    for (int k = 0; k < 128; ++k) acc = fmaf(x[k], tm_W1[k * 256 + o], acc);
    hid[o] = silu_f(acc);
  }
  __syncthreads();
  {
    float acc = tm_b2[j];
    for (int k = 0; k < 256; ++k) acc = fmaf(hid[k], tm_W2[k * 128 + j], acc);
    te[j] = acc;
    temb[g * 128 + j] = acc;
  }
  __syncthreads();
  for (int l = 0; l < LL; ++l) {
    const float* W = eW1 + (l * 385 + 257) * 128;
    float acc = eb1[l * 128 + j];
    for (int k = 0; k < 128; ++k) acc = fmaf(te[k], W[k * 128 + j], acc);
    tE[(l * GN + g) * 128 + j] = acc;
    const float* Wn = nW1 + (l * 384 + 256) * 128;
    float acc2 = nb1[l * 128 + j];
    for (int k = 0; k < 128; ++k) acc2 = fmaf(te[k], Wn[k * 128 + j], acc2);
    tN[(l * GN + g) * 128 + j] = acc2;
  }
}

// ---------------------------------------------------------------------------
// Weight prep: 28 jobs of 128x128 fp32 transpose -> bf16 [n][k] layout.
// job = blockIdx.y: layer l = j/7, matrix m = j%7.
// ---------------------------------------------------------------------------
__global__ __launch_bounds__(256) void prep_transpose(
    const float* __restrict__ eW1, const float* __restrict__ eW2,
    const float* __restrict__ cW1, const float* __restrict__ nW1,
    const float* __restrict__ nW2,
    unsigned short* __restrict__ eABt, unsigned short* __restrict__ eW2t,
    unsigned short* __restrict__ cW1t, unsigned short* __restrict__ nW1t,
    unsigned short* __restrict__ nW2t)
{
  __shared__ float tile[32][33];
  int j = blockIdx.y;
  int l = j / 7, m = j % 7;
  const float* src;
  unsigned short* dst;
  int dstride;
  switch (m) {
    case 0: src = eW1 + (l * 385 + 0) * 128;   dst = eABt + l * 256 * 128;            dstride = 128; break;
    case 1: src = eW1 + (l * 385 + 128) * 128; dst = eABt + l * 256 * 128 + 128 * 128; dstride = 128; break;
    case 2: src = eW2 + l * 16384;             dst = eW2t + l * 16384;                dstride = 128; break;
    case 3: src = cW1 + l * 16384;             dst = cW1t + l * 16384;                dstride = 128; break;
    case 4: src = nW1 + (l * 384 + 0) * 128;   dst = nW1t + l * 128 * 256;            dstride = 256; break;
    case 5: src = nW1 + (l * 384 + 128) * 128; dst = nW1t + l * 128 * 256 + 128;      dstride = 256; break;
    default: src = nW2 + l * 16384;            dst = nW2t + l * 16384;                dstride = 128; break;
  }
  int tk = (blockIdx.x & 3) * 32;   // k-tile
  int tn = (blockIdx.x >> 2) * 32;  // n-tile
  int ti = threadIdx.x >> 5, tj = threadIdx.x & 31;
#pragma unroll
  for (int p = 0; p < 4; ++p) {
    int i = ti + p * 8;
    tile[i][tj] = src[(tk + i) * 128 + tn + tj];
  }
  __syncthreads();
#pragma unroll
  for (int p = 0; p < 4; ++p) {
    int i = ti + p * 8;
    dst[(tn + i) * dstride + tk + tj] = f2bu(tile[tj][i]);
  }
}

// ---------------------------------------------------------------------------
// Old fp32 node GEMM (used only for the encoder with species gather).
// ---------------------------------------------------------------------------
__global__ __launch_bounds__(256) void gemm_node(
    const float* __restrict__ A0, int K0,
    const float* __restrict__ A1, int K1, const int* __restrict__ idx1, int a1rows,
    const float* __restrict__ W, const float* __restrict__ bias,
    float* __restrict__ out, int ldout)
{
  __shared__ float Ast[32 * 36];
  __shared__ float Wsf[32 * 128];
  int t = threadIdx.x;
  int rowBase = blockIdx.x * 32;
  int tx = t & 31;
  int ty = t >> 5;
  int Ktot = K0 + K1;
  float acc[4][4] = {{0.f, 0.f, 0.f, 0.f}, {0.f, 0.f, 0.f, 0.f},
                     {0.f, 0.f, 0.f, 0.f}, {0.f, 0.f, 0.f, 0.f}};
  int lr = t >> 3, lkq = t & 7;

  for (int kk = 0; kk < Ktot; kk += 32) {
    __syncthreads();
    {
      int grow = rowBase + lr;
      int kcol = kk + lkq * 4;
      float4 v;
      if (kcol < K0) {
        v = *(const float4*)(A0 + grow * K0 + kcol);
      } else {
        int arow = grow;
        if (idx1) { arow = idx1[grow]; arow = min(max(arow, 0), a1rows - 1); }
        v = *(const float4*)(A1 + arow * K1 + (kcol - K0));
      }
      Ast[(lkq * 4 + 0) * 36 + lr] = v.x;
      Ast[(lkq * 4 + 1) * 36 + lr] = v.y;
      Ast[(lkq * 4 + 2) * 36 + lr] = v.z;
      Ast[(lkq * 4 + 3) * 36 + lr] = v.w;
    }
    for (int fi = t; fi < 1024; fi += 256)
      ((float4*)Wsf)[fi] = ((const float4*)W)[kk * 32 + fi];
    __syncthreads();
#pragma unroll
    for (int k = 0; k < 32; ++k) {
      float4 a = *(const float4*)&Ast[k * 36 + ty * 4];
      float4 w = *(const float4*)&Wsf[k * 128 + tx * 4];
      float av[4] = {a.x, a.y, a.z, a.w};
      float wv[4] = {w.x, w.y, w.z, w.w};
#pragma unroll
      for (int i = 0; i < 4; ++i)
#pragma unroll
        for (int q = 0; q < 4; ++q)
          acc[i][q] = fmaf(av[i], wv[q], acc[i][q]);
    }
  }
#pragma unroll
  for (int i = 0; i < 4; ++i) {
    int grow = rowBase + ty * 4 + i;
#pragma unroll
    for (int q = 0; q < 4; ++q) {
      int col = tx * 4 + q;
      float v = acc[i][q];
      if (bias) v += bias[col];
      out[grow * ldout + col] = v;
    }
  }
}

// ---------------------------------------------------------------------------
// MFMA node GEMM. Block = 32 rows x NC cols, 256 threads (4 waves).
// wave w: rows (w&1)*16, cols (w>>1)*(NC/2). A fp32 from global (cvt bf16),
// Wt bf16 [NC][KT32*32] pre-transposed. No LDS.
// ---------------------------------------------------------------------------
template <int NC16, int KT32>
__global__ __launch_bounds__(256) void gemm_mfma(
    const float* __restrict__ A0, int K0, const float* __restrict__ A1,
    const unsigned short* __restrict__ Wt,
    const float* __restrict__ bias, const float* __restrict__ extra,
    void* __restrict__ outp, int ldout, int act, int addto, int outBf16)
{
  int t = threadIdx.x;
  int w = t >> 6, l6 = t & 63;
  int m = l6 & 15, q = l6 >> 4;
  int rowBase = blockIdx.x * 32 + (w & 1) * 16;
  int ctBase = (w >> 1) * (NC16 / 2);
  int arow = rowBase + m;

  f32x4 acc[NC16 / 2];
#pragma unroll
  for (int c = 0; c < NC16 / 2; ++c) acc[c] = (f32x4){0.f, 0.f, 0.f, 0.f};

#pragma unroll
  for (int kc = 0; kc < KT32; ++kc) {
    int k = kc * 32 + q * 8;
    const float* src = (k < K0) ? (A0 + arow * K0 + k)
                                : (A1 + arow * 128 + (k - K0));
    float4 f0 = *(const float4*)src;
    float4 f1 = *(const float4*)(src + 4);
    short8 af;
    af[0] = (short)f2bu(f0.x); af[1] = (short)f2bu(f0.y);
    af[2] = (short)f2bu(f0.z); af[3] = (short)f2bu(f0.w);
    af[4] = (short)f2bu(f1.x); af[5] = (short)f2bu(f1.y);
    af[6] = (short)f2bu(f1.z); af[7] = (short)f2bu(f1.w);
#pragma unroll
    for (int c = 0; c < NC16 / 2; ++c) {
      int ctg = ctBase + c;
      short8 bf = *(const short8*)(Wt + (ctg * 16 + m) * (KT32 * 32) + kc * 32 + q * 8);
      acc[c] = __builtin_amdgcn_mfma_f32_16x16x32_bf16(af, bf, acc[c], 0, 0, 0);
    }
  }
#pragma unroll
  for (int c = 0; c < NC16 / 2; ++c) {
    int col = (ctBase + c) * 16 + m;
#pragma unroll
    for (int r = 0; r < 4; ++r) {
      int row = rowBase + q * 4 + r;
      float v = acc[c][r];
      if (bias) v += bias[col];
      if (extra) v += extra[(row / NPER) * 128 + col];
      if (act) v = silu_f(v);
      if (outBf16) {
        ((unsigned short*)outp)[row * ldout + col] = f2bu(v);
      } else {
        float* p = (float*)outp + row * ldout + col;
        if (addto) *p += v; else *p = v;
      }
    }
  }
}

// ---------------------------------------------------------------------------
// Edge pipeline, MFMA version. Block = 8 nodes = 96 edges, 256 threads.
// m1 = silu(hA[src]+hB[dst]+dist_sq*wd+tE[g])  (bf16, LDS)
// m2 = silu(m1 @ eW2 + eb2)                     (MFMA, back into same LDS)
// g  = silu(m2 @ cW1 + cb1); gate = g . cW2     (MFMA, regs + shfl reduce)
// m_i[n] = sum_12 m2;  shift[n] (+)= sum_12 diff/dist*gate
// ---------------------------------------------------------------------------
__global__ __launch_bounds__(256) void edge_mfma(
    const unsigned short* __restrict__ hAB,   // [NN][256] bf16
    const float* __restrict__ coords, const int* __restrict__ edge_src,
    const float* __restrict__ eW1,            // fp32, for dist_sq row
    const unsigned short* __restrict__ eW2t, const float* __restrict__ eb2,
    const unsigned short* __restrict__ cW1t, const float* __restrict__ cb1,
    const float* __restrict__ cW2, const float* __restrict__ tE,
    float* __restrict__ m_i, float* __restrict__ shift_out,
    int l, int addflag)
{
  __shared__ unsigned short mbuf[96 * 136];
  __shared__ float sdx[96], sdy[96], sdz[96], sds[96], sinvd[96];
  __shared__ float sgate[96][4];
  __shared__ int ssrc[96];

  int t = threadIdx.x;
  int w = t >> 6, l6 = t & 63;
  int m = l6 & 15, q = l6 >> 4;
  int nbase = blockIdx.x * 8;
  int ebase = nbase * 12;

  const unsigned short* eW2t_l = eW2t + l * 16384;
  const unsigned short* cW1t_l = cW1t + l * 16384;
  const float* eb2_l = eb2 + l * 128;
  const float* cb1_l = cb1 + l * 128;
  const float* cW2_l = cW2 + l * 128;
  const float* tE_l  = tE + l * GN * 128;
  const float* wd    = eW1 + (l * 385 + 256) * 128;

  if (t < 96) {
    int e = ebase + t;
    int src = edge_src[e];
    src = min(max(src, 0), NN - 1);
    int dst = nbase + t / 12;
    float dx = coords[src * 3 + 0] - coords[dst * 3 + 0];
    float dy = coords[src * 3 + 1] - coords[dst * 3 + 1];
    float dz = coords[src * 3 + 2] - coords[dst * 3 + 2];
    float ds = dx * dx + dy * dy + dz * dz;
    ssrc[t] = src;
    sdx[t] = dx; sdy[t] = dy; sdz[t] = dz; sds[t] = ds;
    sinvd[t] = 1.0f / sqrtf(ds + 1e-8f);
  }
  __syncthreads();

  // Phase A: m1 (bf16 into mbuf)
  for (int idx = t; idx < 96 * 32; idx += 256) {
    int e = idx >> 5;
    int j4 = (idx & 31) << 2;
    int src = ssrc[e];
    int dstn = nbase + (e / 12);
    int g = dstn / NPER;
    ushort4 ua = *(const ushort4*)(hAB + src * 256 + j4);
    ushort4 ub = *(const ushort4*)(hAB + dstn * 256 + 128 + j4);
    float4 wv = *(const float4*)(wd + j4);
    float4 tv = *(const float4*)(tE_l + g * 128 + j4);
    float ds = sds[e];
    float v0 = silu_f(bs2f(ua.x) + bs2f(ub.x) + ds * wv.x + tv.x);
    float v1 = silu_f(bs2f(ua.y) + bs2f(ub.y) + ds * wv.y + tv.y);
    float v2 = silu_f(bs2f(ua.z) + bs2f(ub.z) + ds * wv.z + tv.z);
    float v3 = silu_f(bs2f(ua.w) + bs2f(ub.w) + ds * wv.w + tv.w);
    ushort4 o;
    o.x = f2bu(v0); o.y = f2bu(v1); o.z = f2bu(v2); o.w = f2bu(v3);
    *(ushort4*)(mbuf + e * 136 + j4) = o;
  }
  __syncthreads();

  // ---- GEMM 1: m2 = silu(m1 @ eW2 + eb2) ----
  {
    short8 bB[2][4];
#pragma unroll
    for (int c = 0; c < 2; ++c)
#pragma unroll
      for (int kc = 0; kc < 4; ++kc)
        bB[c][kc] = *(const short8*)(eW2t_l + ((w * 2 + c) * 16 + m) * 128 + kc * 32 + q * 8);
    f32x4 acc[6][2];
#pragma unroll
    for (int rt = 0; rt < 6; ++rt) { acc[rt][0] = (f32x4){0,0,0,0}; acc[rt][1] = (f32x4){0,0,0,0}; }
#pragma unroll
    for (int rt = 0; rt < 6; ++rt) {
      short8 af[4];
#pragma unroll
      for (int kc = 0; kc < 4; ++kc)
        af[kc] = *(const short8*)(mbuf + (rt * 16 + m) * 136 + kc * 32 + q * 8);
#pragma unroll
      for (int kc = 0; kc < 4; ++kc) {
        acc[rt][0] = __builtin_amdgcn_mfma_f32_16x16x32_bf16(af[kc], bB[0][kc], acc[rt][0], 0, 0, 0);
        acc[rt][1] = __builtin_amdgcn_mfma_f32_16x16x32_bf16(af[kc], bB[1][kc], acc[rt][1], 0, 0, 0);
      }
    }
    __syncthreads();   // all waves done reading m1
#pragma unroll
    for (int rt = 0; rt < 6; ++rt)
#pragma unroll
      for (int c = 0; c < 2; ++c) {
        int col = (w * 2 + c) * 16 + m;
        float b = eb2_l[col];
#pragma unroll
        for (int r = 0; r < 4; ++r) {
          int row = rt * 16 + q * 4 + r;
          mbuf[row * 136 + col] = f2bu(silu_f(acc[rt][c][r] + b));
        }
      }
  }
  __syncthreads();

  // ---- GEMM 2: g = silu(m2 @ cW1 + cb1); gate = g . cW2 ----
  {
    short8 bC[2][4];
#pragma unroll
    for (int c = 0; c < 2; ++c)
#pragma unroll
      for (int kc = 0; kc < 4; ++kc)
        bC[c][kc] = *(const short8*)(cW1t_l + ((w * 2 + c) * 16 + m) * 128 + kc * 32 + q * 8);
    float cb[2], c2[2];
#pragma unroll
    for (int c = 0; c < 2; ++c) {
      int col = (w * 2 + c) * 16 + m;
      cb[c] = cb1_l[col];
      c2[c] = cW2_l[col];
    }
#pragma unroll
    for (int rt = 0; rt < 6; ++rt) {
      f32x4 a0 = (f32x4){0,0,0,0}, a1 = (f32x4){0,0,0,0};
      short8 af[4];
#pragma unroll
      for (int kc = 0; kc < 4; ++kc)
        af[kc] = *(const short8*)(mbuf + (rt * 16 + m) * 136 + kc * 32 + q * 8);
#pragma unroll
      for (int kc = 0; kc < 4; ++kc) {
        a0 = __builtin_amdgcn_mfma_f32_16x16x32_bf16(af[kc], bC[0][kc], a0, 0, 0, 0);
        a1 = __builtin_amdgcn_mfma_f32_16x16x32_bf16(af[kc], bC[1][kc], a1, 0, 0, 0);
      }
      float gv[4];
#pragma unroll
      for (int r = 0; r < 4; ++r)
        gv[r] = silu_f(a0[r] + cb[0]) * c2[0] + silu_f(a1[r] + cb[1]) * c2[1];
#pragma unroll
      for (int mask = 1; mask < 16; mask <<= 1)
#pragma unroll
        for (int r = 0; r < 4; ++r) gv[r] += __shfl_xor(gv[r], mask, 64);
      if (m == 0) {
#pragma unroll
        for (int r = 0; r < 4; ++r) sgate[rt * 16 + q * 4 + r][w] = gv[r];
      }
    }
  }
  __syncthreads();

  // m_i: sum of m2 over each node's 12 edges
  for (int idx = t; idx < 8 * 128; idx += 256) {
    int nl = idx >> 7, j = idx & 127;
    float s = 0.f;
#pragma unroll
    for (int r = 0; r < 12; ++r) s += bs2f(mbuf[(nl * 12 + r) * 136 + j]);
    m_i[(nbase + nl) * 128 + j] = s;
  }
  // shift accumulation
  if (t < 24) {
    int nl = t / 3, c = t % 3;
    float s = 0.f;
#pragma unroll
    for (int r = 0; r < 12; ++r) {
      int e = nl * 12 + r;
      float g = sgate[e][0] + sgate[e][1] + sgate[e][2] + sgate[e][3];
      float comp = (c == 0) ? sdx[e] : ((c == 1) ? sdy[e] : sdz[e]);
      s = fmaf(comp * sinvd[e], g, s);
    }
    int n = nbase + nl;
    if (addflag) shift_out[n * 3 + c] += s;
    else         shift_out[n * 3 + c] = s;
  }
}

extern "C" void kernel_launch(void* const* d_in, const int* in_sizes, int n_in,
                              void* d_out, int out_size, void* d_ws, size_t ws_size,
                              hipStream_t stream)
{
  const float* z_nodes     = (const float*)d_in[0];
  const float* t           = (const float*)d_in[1];
  const float* coords      = (const float*)d_in[2];
  const int*   species     = (const int*)d_in[3];
  const int*   edge_src    = (const int*)d_in[5];
  const float* species_emb = (const float*)d_in[7];
  const float* tm_W1 = (const float*)d_in[8];
  const float* tm_b1 = (const float*)d_in[9];
  const float* tm_W2 = (const float*)d_in[10];
  const float* tm_b2 = (const float*)d_in[11];
  const float* ne_W  = (const float*)d_in[12];
  const float* ne_b  = (const float*)d_in[13];
  const float* eW1   = (const float*)d_in[14];
  const float* eb1   = (const float*)d_in[15];
  const float* eW2   = (const float*)d_in[16];
  const float* eb2   = (const float*)d_in[17];
  const float* cW1   = (const float*)d_in[18];
  const float* cb1   = (const float*)d_in[19];
  const float* cW2   = (const float*)d_in[20];
  const float* nW1   = (const float*)d_in[21];
  const float* nb1   = (const float*)d_in[22];
  const float* nW2   = (const float*)d_in[23];
  const float* nb2   = (const float*)d_in[24];

  char* wsb = (char*)d_ws;
  float* temb = (float*)(wsb + 0);                  // 400*128*4      = 204800
  float* tEb  = (float*)(wsb + 204800);             // 4*400*128*4    = 819200
  float* tNb  = (float*)(wsb + 1024000);            // 819200
  unsigned short* hAB = (unsigned short*)(wsb + 1843200);   // 20000*256*2 = 10,240,000
  float* z1   = (float*)(wsb + 1843200);            // alias hAB (dead after edge kernel)
  float* m_i  = (float*)(wsb + 12083200);           // 20000*128*4 = 10,240,000
  unsigned short* eABt = (unsigned short*)(wsb + 22323200); // 4*256*128*2 = 262144
  unsigned short* eW2t = (unsigned short*)(wsb + 22585344); // 131072
  unsigned short* cW1t = (unsigned short*)(wsb + 22716416); // 131072
  unsigned short* nW1t = (unsigned short*)(wsb + 22847488); // 4*128*256*2 = 262144
  unsigned short* nW2t = (unsigned short*)(wsb + 23109632); // 131072
  // total ws use: 23,240,704 bytes

  float* outp  = (float*)d_out;
  float* shift = outp;            // [20000,3]
  float* h     = outp + 60000;    // [20000,128]

  time_kernel<<<GN, 128, 0, stream>>>(t, tm_W1, tm_b1, tm_W2, tm_b2,
                                      eW1, eb1, nW1, nb1, temb, tEb, tNb);
  prep_transpose<<<dim3(16, 28), 256, 0, stream>>>(eW1, eW2, cW1, nW1, nW2,
                                                   eABt, eW2t, cW1t, nW1t, nW2t);
  // encoder: h = [z | sp(species)] @ ne_W + ne_b (fp32, keeps gather exact)
  gemm_node<<<NN / 32, 256, 0, stream>>>(z_nodes, 128, species_emb, 32, species, 119,
                                         ne_W, ne_b, h, 128);

  for (int l = 0; l < LL; ++l) {
    // hAB[n] = [h@Wa | h@Wb]  (bf16 out)
    gemm_mfma<16, 4><<<NN / 32, 256, 0, stream>>>(
        h, 128, nullptr, eABt + l * 256 * 128, nullptr, nullptr,
        (void*)hAB, 256, 0, 0, 1);
    // edge pipeline
    edge_mfma<<<NN / 8, 256, 0, stream>>>(hAB, coords, edge_src, eW1,
                                          eW2t, eb2, cW1t, cb1, cW2, tEb,
                                          m_i, shift, l, (l > 0) ? 1 : 0);
    // z1 = silu([h | m_i] @ nW1[0:256] + tN)   (nb1 folded into tN)
    gemm_mfma<8, 8><<<NN / 32, 256, 0, stream>>>(
        h, 128, m_i, nW1t + l * 128 * 256, nullptr, tNb + l * 51200,
        (void*)z1, 128, 1, 0, 0);
    // h += z1 @ nW2 + nb2
    gemm_mfma<8, 4><<<NN / 32, 256, 0, stream>>>(
        z1, 128, nullptr, nW2t + l * 16384, nb2 + l * 128, nullptr,
        (void*)h, 128, 0, 1, 0);
  }
}

// Round 4
// 550.333 us; speedup vs baseline: 3.3381x; 1.3010x over previous
//
#include <hip/hip_runtime.h>
#include <math.h>

#define GN 400
#define NPER 50
#define NN 20000
#define LL 4

typedef __attribute__((ext_vector_type(8))) short short8;
typedef __attribute__((ext_vector_type(4))) float f32x4;

__device__ __forceinline__ float fast_rcp(float x) {
#if __has_builtin(__builtin_amdgcn_rcpf)
  return __builtin_amdgcn_rcpf(x);
#else
  return 1.0f / x;
#endif
}
__device__ __forceinline__ float silu_f(float x) {
  return x * fast_rcp(1.0f + __expf(-x));
}
__device__ __forceinline__ unsigned short f2bu(float f) {
  unsigned int u = __float_as_uint(f);
  unsigned int r = (u + 0x7fffu + ((u >> 16) & 1u)) >> 16;
  return (unsigned short)r;
}
__device__ __forceinline__ unsigned int pack2bf(float lo, float hi) {
  return (unsigned int)f2bu(lo) | ((unsigned int)f2bu(hi) << 16);
}
__device__ __forceinline__ float bhi(unsigned int u) { return __uint_as_float(u & 0xffff0000u); }
__device__ __forceinline__ float blo(unsigned int u) { return __uint_as_float(u << 16); }

__device__ __forceinline__ short8 pack8(const float* v) {
  union { unsigned int u[4]; short8 s; } t;
  t.u[0] = pack2bf(v[0], v[1]);
  t.u[1] = pack2bf(v[2], v[3]);
  t.u[2] = pack2bf(v[4], v[5]);
  t.u[3] = pack2bf(v[6], v[7]);
  return t.s;
}

// ---------------------------------------------------------------------------
// Time embedding MLP + per-layer per-graph t-projections (400 graphs)
// tE[l][g] = temb[g] @ eW1[l][257:385] + eb1[l];  tN[l][g] = temb[g] @ nW1[l][256:384] + nb1[l]
// ---------------------------------------------------------------------------
__global__ __launch_bounds__(128) void time_kernel(
    const float* __restrict__ t,
    const float* __restrict__ tm_W1, const float* __restrict__ tm_b1,
    const float* __restrict__ tm_W2, const float* __restrict__ tm_b2,
    const float* __restrict__ eW1, const float* __restrict__ eb1,
    const float* __restrict__ nW1, const float* __restrict__ nb1,
    float* __restrict__ temb, float* __restrict__ tE, float* __restrict__ tN)
{
  int g = blockIdx.x;
  int j = threadIdx.x;
  __shared__ float x[128];
  __shared__ float hid[256];
  __shared__ float te[128];
  float tv = t[g];
  if (j < 64) {
    float f = __expf((float)j * (-9.210340371976184f / 63.0f));
    float a = tv * f;
    x[j] = sinf(a);
    x[j + 64] = cosf(a);
  }
  __syncthreads();
  for (int o = j; o < 256; o += 128) {
    float acc = tm_b1[o];
    for (int k = 0; k < 128; ++k) acc = fmaf(x[k], tm_W1[k * 256 + o], acc);
    hid[o] = silu_f(acc);
  }
  __syncthreads();
  {
    float acc = tm_b2[j];
    for (int k = 0; k < 256; ++k) acc = fmaf(hid[k], tm_W2[k * 128 + j], acc);
    te[j] = acc;
    temb[g * 128 + j] = acc;
  }
  __syncthreads();
  for (int l = 0; l < LL; ++l) {
    const float* W = eW1 + (l * 385 + 257) * 128;
    float acc = eb1[l * 128 + j];
    for (int k = 0; k < 128; ++k) acc = fmaf(te[k], W[k * 128 + j], acc);
    tE[(l * GN + g) * 128 + j] = acc;
    const float* Wn = nW1 + (l * 384 + 256) * 128;
    float acc2 = nb1[l * 128 + j];
    for (int k = 0; k < 128; ++k) acc2 = fmaf(te[k], Wn[k * 128 + j], acc2);
    tN[(l * GN + g) * 128 + j] = acc2;
  }
}

// ---------------------------------------------------------------------------
// Weight prep: fp32 [K][128] -> bf16 transposed [n][k]. Jobs 0..27 K=128,
// job 28 = ne_W with K=160.
// ---------------------------------------------------------------------------
__global__ __launch_bounds__(256) void prep_transpose(
    const float* __restrict__ eW1, const float* __restrict__ eW2,
    const float* __restrict__ cW1, const float* __restrict__ nW1,
    const float* __restrict__ nW2, const float* __restrict__ ne_W,
    unsigned short* __restrict__ eABt, unsigned short* __restrict__ eW2t,
    unsigned short* __restrict__ cW1t, unsigned short* __restrict__ nW1t,
    unsigned short* __restrict__ nW2t, unsigned short* __restrict__ ne_Wt)
{
  __shared__ float tile[32][33];
  int j = blockIdx.y;
  const float* src;
  unsigned short* dst;
  int dstride = 128, Kj = 128;
  if (j < 28) {
    int l = j / 7, m = j % 7;
    switch (m) {
      case 0: src = eW1 + (l * 385 + 0) * 128;   dst = eABt + l * 256 * 128;             break;
      case 1: src = eW1 + (l * 385 + 128) * 128; dst = eABt + l * 256 * 128 + 128 * 128; break;
      case 2: src = eW2 + l * 16384;             dst = eW2t + l * 16384;                 break;
      case 3: src = cW1 + l * 16384;             dst = cW1t + l * 16384;                 break;
      case 4: src = nW1 + (l * 384 + 0) * 128;   dst = nW1t + l * 128 * 256; dstride = 256; break;
      case 5: src = nW1 + (l * 384 + 128) * 128; dst = nW1t + l * 128 * 256 + 128; dstride = 256; break;
      default: src = nW2 + l * 16384;            dst = nW2t + l * 16384;                 break;
    }
  } else {
    src = ne_W; dst = ne_Wt; dstride = 160; Kj = 160;
  }
  int gx = blockIdx.x;
  int tk = (gx % 5) * 32;
  int tn = (gx / 5) * 32;
  if (tk >= Kj) return;
  int ti = threadIdx.x >> 5, tj = threadIdx.x & 31;
#pragma unroll
  for (int p = 0; p < 4; ++p) {
    int i = ti + p * 8;
    tile[i][tj] = src[(tk + i) * 128 + tn + tj];
  }
  __syncthreads();
#pragma unroll
  for (int p = 0; p < 4; ++p) {
    int i = ti + p * 8;
    dst[(tn + i) * dstride + tk + tj] = f2bu(tile[tj][i]);
  }
}

// ---------------------------------------------------------------------------
// Edge pipeline: 1 wave per block, 48 edges = 4 nodes. Zero inter-wave
// barriers (single-wave ordering syncs only).
// m1 fragments built directly in registers; GEMM1 computed transposed so m2
// lands in LDS via packed b64 writes; GEMM2 reads b128 A-frags.
// ---------------------------------------------------------------------------
__global__ __launch_bounds__(64) void edge_mfma(
    const unsigned short* __restrict__ hAB,   // [NN][256] bf16
    const float* __restrict__ coords, const int* __restrict__ edge_src,
    const float* __restrict__ eW1,            // fp32 (dist_sq row)
    const unsigned short* __restrict__ eW2t, const float* __restrict__ eb2,
    const unsigned short* __restrict__ cW1t, const float* __restrict__ cb1,
    const float* __restrict__ cW2, const float* __restrict__ tE,
    unsigned short* __restrict__ m_i, float* __restrict__ shift_out,
    int l, int addflag)
{
  __shared__ unsigned short mbuf[48 * 136];
  __shared__ float sdir[48 * 4];
  __shared__ float sgate[48];

  int l6 = threadIdx.x;
  int e16 = l6 & 15, q = l6 >> 4;
  int nbase = blockIdx.x * 4;
  int ebase = blockIdx.x * 48;

  const unsigned short* eW2t_l = eW2t + l * 16384;
  const unsigned short* cW1t_l = cW1t + l * 16384;
  const float* eb2_l = eb2 + l * 128;
  const float* cb1_l = cb1 + l * 128;
  const float* cW2_l = cW2 + l * 128;
  const float* tE_l = tE + l * GN * 128;
  const float* wd = eW1 + (l * 385 + 256) * 128;

  // geometry per group of 16 edges
  int ssrc[3], sdst[3];
  float sds[3];
#pragma unroll
  for (int grp = 0; grp < 3; ++grp) {
    int eloc = grp * 16 + e16;
    int e = ebase + eloc;
    int src = edge_src[e];
    src = min(max(src, 0), NN - 1);   // defensive clamp
    int dst = nbase + eloc / 12;
    float dx = coords[src * 3 + 0] - coords[dst * 3 + 0];
    float dy = coords[src * 3 + 1] - coords[dst * 3 + 1];
    float dz = coords[src * 3 + 2] - coords[dst * 3 + 2];
    float ds = dx * dx + dy * dy + dz * dz;
    float rinv = 1.0f / sqrtf(ds + 1e-8f);
    if (q == 0) {
      sdir[eloc * 4 + 0] = dx * rinv;
      sdir[eloc * 4 + 1] = dy * rinv;
      sdir[eloc * 4 + 2] = dz * rinv;
    }
    ssrc[grp] = src; sdst[grp] = dst; sds[grp] = ds;
  }

  // Phase A: m1 B-fragments in registers. lane: edge=e16(+16*grp), k=kc*32+q*8+j
  short8 bfr[3][4];
#pragma unroll
  for (int grp = 0; grp < 3; ++grp) {
    int g = sdst[grp] / NPER;
    float ds = sds[grp];
#pragma unroll
    for (int kc = 0; kc < 4; ++kc) {
      int k0 = kc * 32 + q * 8;
      uint4 ua = *(const uint4*)(hAB + ssrc[grp] * 256 + k0);
      uint4 ub = *(const uint4*)(hAB + sdst[grp] * 256 + 128 + k0);
      float4 w0 = *(const float4*)(wd + k0);
      float4 w1 = *(const float4*)(wd + k0 + 4);
      float4 t0 = *(const float4*)(tE_l + g * 128 + k0);
      float4 t1 = *(const float4*)(tE_l + g * 128 + k0 + 4);
      float v[8];
      v[0] = silu_f(blo(ua.x) + blo(ub.x) + ds * w0.x + t0.x);
      v[1] = silu_f(bhi(ua.x) + bhi(ub.x) + ds * w0.y + t0.y);
      v[2] = silu_f(blo(ua.y) + blo(ub.y) + ds * w0.z + t0.z);
      v[3] = silu_f(bhi(ua.y) + bhi(ub.y) + ds * w0.w + t0.w);
      v[4] = silu_f(blo(ua.z) + blo(ub.z) + ds * w1.x + t1.x);
      v[5] = silu_f(bhi(ua.z) + bhi(ub.z) + ds * w1.y + t1.y);
      v[6] = silu_f(blo(ua.w) + blo(ub.w) + ds * w1.z + t1.z);
      v[7] = silu_f(bhi(ua.w) + bhi(ub.w) + ds * w1.w + t1.w);
      bfr[grp][kc] = pack8(v);
    }
  }

  // GEMM1 (transposed): m2^T = eW2^T @ m1^T. Lane C-frag = 4 contiguous cols
  // of one edge row -> packed b64 LDS writes into mbuf[edge][col].
#pragma unroll
  for (int mt = 0; mt < 8; ++mt) {
    short8 af[4];
#pragma unroll
    for (int kc = 0; kc < 4; ++kc)
      af[kc] = *(const short8*)(eW2t_l + (mt * 16 + e16) * 128 + kc * 32 + q * 8);
    f32x4 acc[3] = {(f32x4){0,0,0,0}, (f32x4){0,0,0,0}, (f32x4){0,0,0,0}};
#pragma unroll
    for (int kc = 0; kc < 4; ++kc) {
#pragma unroll
      for (int grp = 0; grp < 3; ++grp)
        acc[grp] = __builtin_amdgcn_mfma_f32_16x16x32_bf16(af[kc], bfr[grp][kc], acc[grp], 0, 0, 0);
    }
    float4 b4 = *(const float4*)(eb2_l + mt * 16 + q * 4);
#pragma unroll
    for (int grp = 0; grp < 3; ++grp) {
      float v0 = silu_f(acc[grp][0] + b4.x);
      float v1 = silu_f(acc[grp][1] + b4.y);
      float v2 = silu_f(acc[grp][2] + b4.z);
      float v3 = silu_f(acc[grp][3] + b4.w);
      uint2 p;
      p.x = pack2bf(v0, v1);
      p.y = pack2bf(v2, v3);
      *(uint2*)&mbuf[(grp * 16 + e16) * 136 + mt * 16 + q * 4] = p;
    }
  }
  __syncthreads();  // single wave: ordering only

  // GEMM2: g = m2 @ cW1; gate = g . cW2 (in-register reduce)
  short8 af2[3][4];
#pragma unroll
  for (int grp = 0; grp < 3; ++grp)
#pragma unroll
    for (int kc = 0; kc < 4; ++kc)
      af2[grp][kc] = *(const short8*)&mbuf[(grp * 16 + e16) * 136 + kc * 32 + q * 8];

  float gp[3][4] = {{0,0,0,0},{0,0,0,0},{0,0,0,0}};
#pragma unroll
  for (int ct = 0; ct < 8; ++ct) {
    short8 bf[4];
#pragma unroll
    for (int kc = 0; kc < 4; ++kc)
      bf[kc] = *(const short8*)(cW1t_l + (ct * 16 + e16) * 128 + kc * 32 + q * 8);
    f32x4 acc[3] = {(f32x4){0,0,0,0}, (f32x4){0,0,0,0}, (f32x4){0,0,0,0}};
#pragma unroll
    for (int kc = 0; kc < 4; ++kc) {
#pragma unroll
      for (int grp = 0; grp < 3; ++grp)
        acc[grp] = __builtin_amdgcn_mfma_f32_16x16x32_bf16(af2[grp][kc], bf[kc], acc[grp], 0, 0, 0);
    }
    float cb = cb1_l[ct * 16 + e16];
    float c2 = cW2_l[ct * 16 + e16];
#pragma unroll
    for (int grp = 0; grp < 3; ++grp)
#pragma unroll
      for (int r = 0; r < 4; ++r)
        gp[grp][r] += silu_f(acc[grp][r] + cb) * c2;
  }
#pragma unroll
  for (int grp = 0; grp < 3; ++grp)
#pragma unroll
    for (int r = 0; r < 4; ++r) {
      float v = gp[grp][r];
      v += __shfl_xor(v, 1);
      v += __shfl_xor(v, 2);
      v += __shfl_xor(v, 4);
      v += __shfl_xor(v, 8);
      if (e16 == 0) sgate[grp * 16 + q * 4 + r] = v;
    }
  __syncthreads();  // ordering

  // m_i: node = q, col-chunk = e16*8 (bf16 out)
  {
    int nl = q, c8 = e16 * 8;
    float s[8] = {0,0,0,0,0,0,0,0};
#pragma unroll
    for (int r = 0; r < 12; ++r) {
      uint4 u = *(const uint4*)&mbuf[(nl * 12 + r) * 136 + c8];
      s[0] += blo(u.x); s[1] += bhi(u.x);
      s[2] += blo(u.y); s[3] += bhi(u.y);
      s[4] += blo(u.z); s[5] += bhi(u.z);
      s[6] += blo(u.w); s[7] += bhi(u.w);
    }
    uint4 o;
    o.x = pack2bf(s[0], s[1]); o.y = pack2bf(s[2], s[3]);
    o.z = pack2bf(s[4], s[5]); o.w = pack2bf(s[6], s[7]);
    *(uint4*)(m_i + (nbase + nl) * 128 + c8) = o;
  }
  // shift
  if (l6 < 12) {
    int nl = l6 / 3, c = l6 - nl * 3;
    float s = 0.f;
#pragma unroll
    for (int r = 0; r < 12; ++r) {
      int e = nl * 12 + r;
      s = fmaf(sdir[e * 4 + c], sgate[e], s);
    }
    int n = nbase + nl;
    if (addflag) shift_out[n * 3 + c] += s;
    else         shift_out[n * 3 + c] = s;
  }
}

// ---------------------------------------------------------------------------
// Fused node MLP: h += silu([h|m_i]@nW1 + tN) @ nW2 + nb2; then (optional)
// hAB = h @ eABt_next. One wave per block, 16 rows. All GEMMs transposed so
// C-frags are row-contiguous (packed LDS writes / float4 global I/O).
// ---------------------------------------------------------------------------
__global__ __launch_bounds__(64) void node_mfma(
    float* __restrict__ h, const unsigned short* __restrict__ m_i,
    const unsigned short* __restrict__ nW1t_l, const unsigned short* __restrict__ nW2t_l,
    const float* __restrict__ nb2_l, const float* __restrict__ tN_l,
    const unsigned short* __restrict__ eABt_next, unsigned short* __restrict__ hAB,
    int has_c)
{
  __shared__ unsigned short z1buf[16 * 136];
  __shared__ unsigned short hbuf[16 * 136];
  int l6 = threadIdx.x, e16 = l6 & 15, q = l6 >> 4;
  int row = blockIdx.x * 16 + e16;
  int g = row / NPER;

  // B-fragments from [h | m_i]
  short8 bfh[8];
#pragma unroll
  for (int kc = 0; kc < 8; ++kc) {
    int k0 = kc * 32 + q * 8;
    if (k0 < 128) {
      float4 f0 = *(const float4*)(h + row * 128 + k0);
      float4 f1 = *(const float4*)(h + row * 128 + k0 + 4);
      float v[8] = {f0.x, f0.y, f0.z, f0.w, f1.x, f1.y, f1.z, f1.w};
      bfh[kc] = pack8(v);
    } else {
      bfh[kc] = *(const short8*)(m_i + row * 128 + (k0 - 128));
    }
  }
  // GEMM-a (transposed): z1^T = nW1^T @ [h|m_i]^T
#pragma unroll
  for (int mt = 0; mt < 8; ++mt) {
    short8 af[8];
#pragma unroll
    for (int kc = 0; kc < 8; ++kc)
      af[kc] = *(const short8*)(nW1t_l + (mt * 16 + e16) * 256 + kc * 32 + q * 8);
    f32x4 acc = (f32x4){0,0,0,0};
#pragma unroll
    for (int kc = 0; kc < 8; ++kc)
      acc = __builtin_amdgcn_mfma_f32_16x16x32_bf16(af[kc], bfh[kc], acc, 0, 0, 0);
    float4 tv = *(const float4*)(tN_l + g * 128 + mt * 16 + q * 4);
    float v0 = silu_f(acc[0] + tv.x);
    float v1 = silu_f(acc[1] + tv.y);
    float v2 = silu_f(acc[2] + tv.z);
    float v3 = silu_f(acc[3] + tv.w);
    uint2 p; p.x = pack2bf(v0, v1); p.y = pack2bf(v2, v3);
    *(uint2*)&z1buf[e16 * 136 + mt * 16 + q * 4] = p;
  }
  __syncthreads();

  // GEMM-b (transposed): h_new^T = nW2^T @ z1^T (+h residual, +nb2)
  short8 zf[4];
#pragma unroll
  for (int kc = 0; kc < 4; ++kc)
    zf[kc] = *(const short8*)&z1buf[e16 * 136 + kc * 32 + q * 8];
#pragma unroll
  for (int mt = 0; mt < 8; ++mt) {
    short8 af[4];
#pragma unroll
    for (int kc = 0; kc < 4; ++kc)
      af[kc] = *(const short8*)(nW2t_l + (mt * 16 + e16) * 128 + kc * 32 + q * 8);
    f32x4 acc = (f32x4){0,0,0,0};
#pragma unroll
    for (int kc = 0; kc < 4; ++kc)
      acc = __builtin_amdgcn_mfma_f32_16x16x32_bf16(af[kc], zf[kc], acc, 0, 0, 0);
    float4 hv = *(const float4*)(h + row * 128 + mt * 16 + q * 4);
    float4 b4 = *(const float4*)(nb2_l + mt * 16 + q * 4);
    float4 o;
    o.x = hv.x + acc[0] + b4.x;
    o.y = hv.y + acc[1] + b4.y;
    o.z = hv.z + acc[2] + b4.z;
    o.w = hv.w + acc[3] + b4.w;
    *(float4*)(h + row * 128 + mt * 16 + q * 4) = o;
    uint2 p; p.x = pack2bf(o.x, o.y); p.y = pack2bf(o.z, o.w);
    *(uint2*)&hbuf[e16 * 136 + mt * 16 + q * 4] = p;
  }
  if (has_c) {
    __syncthreads();
    short8 hf[4];
#pragma unroll
    for (int kc = 0; kc < 4; ++kc)
      hf[kc] = *(const short8*)&hbuf[e16 * 136 + kc * 32 + q * 8];
#pragma unroll
    for (int mt = 0; mt < 16; ++mt) {
      short8 af[4];
#pragma unroll
      for (int kc = 0; kc < 4; ++kc)
        af[kc] = *(const short8*)(eABt_next + (mt * 16 + e16) * 128 + kc * 32 + q * 8);
      f32x4 acc = (f32x4){0,0,0,0};
#pragma unroll
      for (int kc = 0; kc < 4; ++kc)
        acc = __builtin_amdgcn_mfma_f32_16x16x32_bf16(af[kc], hf[kc], acc, 0, 0, 0);
      uint2 p; p.x = pack2bf(acc[0], acc[1]); p.y = pack2bf(acc[2], acc[3]);
      *(uint2*)(hAB + row * 256 + mt * 16 + q * 4) = p;
    }
  }
}

// ---------------------------------------------------------------------------
// Fused encoder: h = [z | sp(species)] @ ne_W + ne_b; hAB = h @ eABt[0]
// ---------------------------------------------------------------------------
__global__ __launch_bounds__(64) void encoder_mfma(
    const float* __restrict__ z, const int* __restrict__ species,
    const float* __restrict__ species_emb,
    const unsigned short* __restrict__ ne_Wt, const float* __restrict__ ne_b,
    const unsigned short* __restrict__ eABt0,
    float* __restrict__ h, unsigned short* __restrict__ hAB)
{
  __shared__ unsigned short hbuf[16 * 136];
  int l6 = threadIdx.x, e16 = l6 & 15, q = l6 >> 4;
  int row = blockIdx.x * 16 + e16;
  int sp = species[row];
  sp = min(max(sp, 0), 118);

  short8 bfh[5];
#pragma unroll
  for (int kc = 0; kc < 5; ++kc) {
    int k0 = kc * 32 + q * 8;
    const float* src = (k0 < 128) ? (z + row * 128 + k0)
                                  : (species_emb + sp * 32 + (k0 - 128));
    float4 f0 = *(const float4*)src;
    float4 f1 = *(const float4*)(src + 4);
    float v[8] = {f0.x, f0.y, f0.z, f0.w, f1.x, f1.y, f1.z, f1.w};
    bfh[kc] = pack8(v);
  }
#pragma unroll
  for (int mt = 0; mt < 8; ++mt) {
    short8 af[5];
#pragma unroll
    for (int kc = 0; kc < 5; ++kc)
      af[kc] = *(const short8*)(ne_Wt + (mt * 16 + e16) * 160 + kc * 32 + q * 8);
    f32x4 acc = (f32x4){0,0,0,0};
#pragma unroll
    for (int kc = 0; kc < 5; ++kc)
      acc = __builtin_amdgcn_mfma_f32_16x16x32_bf16(af[kc], bfh[kc], acc, 0, 0, 0);
    float4 b4 = *(const float4*)(ne_b + mt * 16 + q * 4);
    float4 o;
    o.x = acc[0] + b4.x; o.y = acc[1] + b4.y;
    o.z = acc[2] + b4.z; o.w = acc[3] + b4.w;
    *(float4*)(h + row * 128 + mt * 16 + q * 4) = o;
    uint2 p; p.x = pack2bf(o.x, o.y); p.y = pack2bf(o.z, o.w);
    *(uint2*)&hbuf[e16 * 136 + mt * 16 + q * 4] = p;
  }
  __syncthreads();
  short8 hf[4];
#pragma unroll
  for (int kc = 0; kc < 4; ++kc)
    hf[kc] = *(const short8*)&hbuf[e16 * 136 + kc * 32 + q * 8];
#pragma unroll
  for (int mt = 0; mt < 16; ++mt) {
    short8 af[4];
#pragma unroll
    for (int kc = 0; kc < 4; ++kc)
      af[kc] = *(const short8*)(eABt0 + (mt * 16 + e16) * 128 + kc * 32 + q * 8);
    f32x4 acc = (f32x4){0,0,0,0};
#pragma unroll
    for (int kc = 0; kc < 4; ++kc)
      acc = __builtin_amdgcn_mfma_f32_16x16x32_bf16(af[kc], hf[kc], acc, 0, 0, 0);
    uint2 p; p.x = pack2bf(acc[0], acc[1]); p.y = pack2bf(acc[2], acc[3]);
    *(uint2*)(hAB + row * 256 + mt * 16 + q * 4) = p;
  }
}

extern "C" void kernel_launch(void* const* d_in, const int* in_sizes, int n_in,
                              void* d_out, int out_size, void* d_ws, size_t ws_size,
                              hipStream_t stream)
{
  const float* z_nodes     = (const float*)d_in[0];
  const float* t           = (const float*)d_in[1];
  const float* coords      = (const float*)d_in[2];
  const int*   species     = (const int*)d_in[3];
  const int*   edge_src    = (const int*)d_in[5];
  const float* species_emb = (const float*)d_in[7];
  const float* tm_W1 = (const float*)d_in[8];
  const float* tm_b1 = (const float*)d_in[9];
  const float* tm_W2 = (const float*)d_in[10];
  const float* tm_b2 = (const float*)d_in[11];
  const float* ne_W  = (const float*)d_in[12];
  const float* ne_b  = (const float*)d_in[13];
  const float* eW1   = (const float*)d_in[14];
  const float* eb1   = (const float*)d_in[15];
  const float* eW2   = (const float*)d_in[16];
  const float* eb2   = (const float*)d_in[17];
  const float* cW1   = (const float*)d_in[18];
  const float* cb1   = (const float*)d_in[19];
  const float* cW2   = (const float*)d_in[20];
  const float* nW1   = (const float*)d_in[21];
  const float* nb1   = (const float*)d_in[22];
  const float* nW2   = (const float*)d_in[23];
  const float* nb2   = (const float*)d_in[24];

  char* wsb = (char*)d_ws;
  float* temb = (float*)(wsb + 0);                          // 204800 B
  float* tEb  = (float*)(wsb + 204800);                     // 819200 B
  float* tNb  = (float*)(wsb + 1024000);                    // 819200 B
  unsigned short* hAB  = (unsigned short*)(wsb + 1843200);  // 10,240,000 B
  unsigned short* m_i  = (unsigned short*)(wsb + 12083200); // 5,120,000 B (bf16)
  unsigned short* eABt = (unsigned short*)(wsb + 17203200); // 262144
  unsigned short* eW2t = (unsigned short*)(wsb + 17465344); // 131072
  unsigned short* cW1t = (unsigned short*)(wsb + 17596416); // 131072
  unsigned short* nW1t = (unsigned short*)(wsb + 17727488); // 262144
  unsigned short* nW2t = (unsigned short*)(wsb + 17989632); // 131072
  unsigned short* ne_Wt= (unsigned short*)(wsb + 18120704); // 40960
  // total: 18,161,664 B

  float* outp  = (float*)d_out;
  float* shift = outp;            // [20000,3]
  float* h     = outp + 60000;    // [20000,128]

  time_kernel<<<GN, 128, 0, stream>>>(t, tm_W1, tm_b1, tm_W2, tm_b2,
                                      eW1, eb1, nW1, nb1, temb, tEb, tNb);
  prep_transpose<<<dim3(20, 29), 256, 0, stream>>>(eW1, eW2, cW1, nW1, nW2, ne_W,
                                                   eABt, eW2t, cW1t, nW1t, nW2t, ne_Wt);
  encoder_mfma<<<NN / 16, 64, 0, stream>>>(z_nodes, species, species_emb,
                                           ne_Wt, ne_b, eABt, h, hAB);
  for (int l = 0; l < LL; ++l) {
    edge_mfma<<<NN / 4, 64, 0, stream>>>(hAB, coords, edge_src, eW1,
                                         eW2t, eb2, cW1t, cb1, cW2, tEb,
                                         m_i, shift, l, (l > 0) ? 1 : 0);
    int has_c = (l < LL - 1) ? 1 : 0;
    node_mfma<<<NN / 16, 64, 0, stream>>>(h, m_i,
                                          nW1t + l * 128 * 256, nW2t + l * 16384,
                                          nb2 + l * 128, tNb + l * GN * 128,
                                          has_c ? (eABt + (l + 1) * 256 * 128) : eABt,
                                          hAB, has_c);
  }
}